// Round 16
// baseline (115.133 us; speedup 1.0000x reference)
//
#include <hip/hip_runtime.h>
#include <hip/hip_bf16.h>
#include <stdint.h>

// MultiHeadAttention: B=2, L=2048, D=1024, H=16, F=64
// cvt -> GEMM qkv (RING-3 LDS, counted vmcnt, raw barrier; q*0.125*log2e, k, V^T)
// -> flash attention (8 waves = 4 q-subtiles x 2 kv-halves, KVB=32, ring-3 LDS,
//    counted vmcnt; fixed-m exp2, in-register P)  [verified round 15]
// -> GEMM proj (fp32 out)
// NOTE 1: launch_bounds min-waves must respect the 64/128/256 VGPR occupancy steps:
//   (256,5) forced VGPR<=64 -> acc spill -> 518MB scratch writes (round 5).
// NOTE 2 (rounds 9-11): ones-MFMA row-sum denominator fails accuracy (~1.3e-2). Keep fp32 lp.
// NOTE 3 (round 13): zv zero-C + cvt_pk_bf16_f32 (RNE) + tree lp-sum verified safe.
// NOTE 4 (round 14): direct global->reg K/V fragment loads are uncoalesced gathers -> LDS only.
// NOTE 5 (round 15): ring-3 + counted vmcnt schedule verified (attn 52.8->46.1us).
//   The residual 4.19e6 = 2^22 LDS "conflicts" are ds_read_b128's inherent 12-vs-8 cyc
//   throughput (m134), not a swizzle bug.
// NOTE 6 (round 16): same ring-3 schedule ported to gemm_bt (4 loads/thread/tile ->
//   vmcnt(4)); __syncthreads before sC reuse in the V^T epilogue.

typedef unsigned short u16;
typedef __attribute__((ext_vector_type(8))) short short8;
typedef __attribute__((ext_vector_type(4))) float f32x4;
typedef __attribute__((ext_vector_type(16))) float f32x16;
typedef __attribute__((ext_vector_type(4))) unsigned int u32x4;

#define MFMA16(a, b, c) __builtin_amdgcn_mfma_f32_16x16x32_bf16((a), (b), (c), 0, 0, 0)
#define MFMA32(a, b, c) __builtin_amdgcn_mfma_f32_32x32x16_bf16((a), (b), (c), 0, 0, 0)

__device__ __forceinline__ u16 f2bf(float x) {
  union { float f; uint32_t u; } v; v.f = x;
  uint32_t r = v.u + 0x7FFFu + ((v.u >> 16) & 1u);
  return (u16)(r >> 16);
}

__device__ __forceinline__ float fexp2(float x) {
#if __has_builtin(__builtin_amdgcn_exp2f)
  return __builtin_amdgcn_exp2f(x);
#else
  return exp2f(x);
#endif
}

// pack two f32 -> two bf16 (round half-up) in one u32 (GEMM epilogue)
__device__ __forceinline__ uint32_t pkbf(float lo, float hi) {
  uint32_t a = __builtin_bit_cast(uint32_t, lo) + 0x8000u;
  uint32_t b = __builtin_bit_cast(uint32_t, hi) + 0x8000u;
  return __builtin_amdgcn_perm(b, a, 0x07060302u);
}

// single-instruction RNE pack: u16[0]=bf16(lo), u16[1]=bf16(hi)
__device__ __forceinline__ uint32_t cvtpk(float lo, float hi) {
  uint32_t r;
  asm("v_cvt_pk_bf16_f32 %0, %1, %2" : "=v"(r) : "v"(lo), "v"(hi));
  return r;
}

__device__ __forceinline__ void gload16(const void* g, void* l) {
  __builtin_amdgcn_global_load_lds((const __attribute__((address_space(1))) void*)g,
                                   (__attribute__((address_space(3))) void*)l, 16, 0, 0);
}

// ---------------- fp32 -> bf16 convert (merged) ----------------
__global__ __launch_bounds__(256) void cvt_all(const float* __restrict__ x,
                                               const float* __restrict__ wq,
                                               const float* __restrict__ wp,
                                               u16* __restrict__ xb,
                                               u16* __restrict__ wqb,
                                               u16* __restrict__ wpb) {
  int i = blockIdx.x * 256 + threadIdx.x;
  const float* s; u16* d; int off;
  if (i < 1048576) { s = x; d = xb; off = i; }
  else if (i < 1835008) { s = wq; d = wqb; off = i - 1048576; }
  else { s = wp; d = wpb; off = i - 1835008; }
  float4 f = reinterpret_cast<const float4*>(s)[off];
  ushort4 o;
  o.x = f2bf(f.x); o.y = f2bf(f.y); o.z = f2bf(f.z); o.w = f2bf(f.w);
  reinterpret_cast<ushort4*>(d)[off] = o;
}

// ---------------- bf16 GEMM: C = A B^T + bias ----------------
// 128x128 tile, BK=32, RING-3 LDS (48 KB), counted vmcnt(4), raw barrier.
template <int EPI>
__global__ __launch_bounds__(256, 4) void gemm_bt(const u16* __restrict__ A,
                                                  const u16* __restrict__ B,
                                                  const float* __restrict__ bias,
                                                  u16* __restrict__ outb,
                                                  float* __restrict__ outf,
                                                  int M, int N, int K) {
  __shared__ u16 smem[24576];  // 48 KB: 3 bufs x (A 4096 | B 4096)
  const int tid = threadIdx.x;
  const int lane = tid & 63;
  const int wid = tid >> 6;
  const int bn = blockIdx.x, bm = blockIdx.y;
  const int row0 = bm * 128, col0 = bn * 128;
  const int wr = wid >> 1, wc = wid & 1;
  const int fr = lane & 15, fq = lane >> 4;

  f32x4 acc[4][4];
  #pragma unroll
  for (int m = 0; m < 4; m++)
    #pragma unroll
    for (int n = 0; n < 4; n++)
      #pragma unroll
      for (int j = 0; j < 4; j++) acc[m][n][j] = 0.f;

  const int cB = tid + 256;
  const int rA1 = tid >> 2, rA2 = cB >> 2;
  const int lA1 = (tid & 3) ^ ((tid >> 3) & 3);
  const int lA2 = (cB & 3) ^ ((cB >> 3) & 3);
  const size_t ga1 = (size_t)rA1 * K + lA1 * 8;
  const size_t ga2 = (size_t)rA2 * K + lA2 * 8;
  const int d1 = tid * 8, d2 = cB * 8;
  const u16* Ab = A + (size_t)row0 * K;
  const u16* Bb = B + (size_t)col0 * K;

  const int sl = (fq ^ ((fr >> 1) & 3)) * 8;
  const int niter = K >> 5;

  auto STAGE = [&](int tt, int buf) {
    u16* s = smem + buf * 8192;
    const size_t k0 = (size_t)tt * 32;
    gload16(Ab + ga1 + k0, s + d1);
    gload16(Ab + ga2 + k0, s + d2);
    gload16(Bb + ga1 + k0, s + 4096 + d1);
    gload16(Bb + ga2 + k0, s + 4096 + d2);
  };

  STAGE(0, 0);
  int sel = 0;
  for (int t = 0; t < niter; t++) {
    const int nb = (sel == 2) ? 0 : sel + 1;
    if (t + 1 < niter) {
      STAGE(t + 1, nb);
      asm volatile("s_waitcnt vmcnt(4)" ::: "memory");  // tile-t loads done; next-tile in flight
    } else {
      asm volatile("s_waitcnt vmcnt(0)" ::: "memory");
    }
    __builtin_amdgcn_s_barrier();
    __builtin_amdgcn_sched_barrier(0);
    const u16* sa = smem + sel * 8192;
    const u16* sb = sa + 4096;
    short8 a[4], b[4];
    #pragma unroll
    for (int m = 0; m < 4; m++)
      a[m] = *(const short8*)&sa[(wr * 64 + m * 16 + fr) * 32 + sl];
    #pragma unroll
    for (int n = 0; n < 4; n++)
      b[n] = *(const short8*)&sb[(wc * 64 + n * 16 + fr) * 32 + sl];
    __builtin_amdgcn_s_setprio(1);
    #pragma unroll
    for (int m = 0; m < 4; m++)
      #pragma unroll
      for (int n = 0; n < 4; n++)
        acc[m][n] = MFMA16(a[m], b[n], acc[m][n]);
    __builtin_amdgcn_s_setprio(0);
    sel = nb;
  }

  if (EPI == 0) {
    if (bn < 16) {
      #pragma unroll
      for (int m = 0; m < 4; m++) {
        #pragma unroll
        for (int n = 0; n < 4; n++) {
          #pragma unroll
          for (int j = 0; j < 4; j++) {
            int r = row0 + wr * 64 + m * 16 + fq * 4 + j;
            int c = col0 + wc * 64 + n * 16 + fr;
            float v = acc[m][n][j] + bias[c];
            int d = c & 1023, h = d >> 6, f = d & 63;
            int bb = r >> 11, ll = r & 2047;
            int bhh = bb * 16 + h;
            if (bn < 8) {
              outb[((size_t)bhh * 2048 + ll) * 64 + f] = f2bf(v * 0.18033688f);
            } else {
              outb[4194304u + ((size_t)bhh * 2048 + ll) * 64 + f] = f2bf(v);
            }
          }
        }
      }
    } else {
      __syncthreads();  // all waves done reading smem before sC reuse
      u16* sC = smem;
      #pragma unroll
      for (int m = 0; m < 4; m++) {
        #pragma unroll
        for (int n = 0; n < 4; n++) {
          int c_local = wc * 64 + n * 16 + fr;
          int r_base = wr * 64 + m * 16 + fq * 4;
          float bi = bias[col0 + c_local];
          uint2 w;
          w.x = pkbf(acc[m][n][0] + bi, acc[m][n][1] + bi);
          w.y = pkbf(acc[m][n][2] + bi, acc[m][n][3] + bi);
          *(uint2*)&sC[c_local * 128 + (r_base ^ ((c_local & 7) << 3))] = w;
        }
      }
      __syncthreads();
      const int h0 = (col0 - 2048) >> 6;
      const int ll0 = row0 & 2047;
      const int bb = row0 >> 11;
      #pragma unroll
      for (int it = 0; it < 8; it++) {
        int chunk = tid + it * 256;
        int row_c = chunk >> 4, off = chunk & 15;
        short8 v = *(const short8*)&sC[row_c * 128 + ((off * 8) ^ ((row_c & 7) << 3))];
        int h = h0 + (row_c >> 6), f = row_c & 63;
        *(short8*)&outb[8388608u + ((size_t)((bb * 16 + h) * 64 + f)) * 2048 + ll0 + off * 8] = v;
      }
    }
  } else {
    #pragma unroll
    for (int m = 0; m < 4; m++)
      #pragma unroll
      for (int n = 0; n < 4; n++)
        #pragma unroll
        for (int j = 0; j < 4; j++) {
          int r = row0 + wr * 64 + m * 16 + fq * 4 + j;
          int c = col0 + wc * 64 + n * 16 + fr;
          outf[(size_t)r * N + c] = acc[m][n][j] + bias[c];
        }
  }
}

// ---------------- flash attention (ring-3, counted vmcnt, raw barrier) ----------------
// 512 thr / 8 waves: wave(qs=wid&3, kh=wid>>2) = 32 q rows x kv-half (1024), KVB=32.
__device__ __forceinline__ void softpack1(const f32x16& st, float& lp,
                                          short8& paA, short8& paB) {
  float e[16];
  #pragma unroll
  for (int r = 0; r < 16; r++) e[r] = fexp2(st[r]);
  float s0 = (e[0] + e[1]) + (e[2] + e[3]);
  float s1 = (e[4] + e[5]) + (e[6] + e[7]);
  float s2 = (e[8] + e[9]) + (e[10] + e[11]);
  float s3 = (e[12] + e[13]) + (e[14] + e[15]);
  lp += (s0 + s1) + (s2 + s3);
  #pragma unroll
  for (int cc = 0; cc < 2; cc++) {
    uint32_t g0 = cvtpk(e[8 * cc + 0], e[8 * cc + 1]);
    uint32_t g1 = cvtpk(e[8 * cc + 2], e[8 * cc + 3]);
    uint32_t g2 = cvtpk(e[8 * cc + 4], e[8 * cc + 5]);
    uint32_t g3 = cvtpk(e[8 * cc + 6], e[8 * cc + 7]);
    asm volatile("v_permlane32_swap_b32 %0, %1" : "+v"(g0), "+v"(g2));
    asm volatile("v_permlane32_swap_b32 %0, %1" : "+v"(g1), "+v"(g3));
    u32x4 t;
    t[0] = g0; t[1] = g1; t[2] = g2; t[3] = g3;
    if (cc == 0) paA = __builtin_bit_cast(short8, t);
    else paB = __builtin_bit_cast(short8, t);
  }
}

__global__ __launch_bounds__(512, 4) void attn_kernel(const u16* __restrict__ qg,
                                                      const u16* __restrict__ kg,
                                                      const u16* __restrict__ vtg,
                                                      u16* __restrict__ y) {
  __shared__ u16 sStage[24576];  // 48 KB: [kh][3 bufs][K 2048 | V 2048] u16
  __shared__ float sL2[128];
  const int x = blockIdx.x;
  const int bh = (x & 7) * 4 + (x >> 7);   // 4 bh per XCD -> K/V L2-resident
  const int qt = (x >> 3) & 15;
  const int tid = threadIdx.x, l = tid & 63, wid = tid >> 6;
  const int qs = wid & 3, kh = wid >> 2;
  const int col = l & 31, hi = l >> 5;
  const size_t base = (size_t)bh * 131072;
  const u16* qp = qg + base;
  const int qrow = qt * 128 + qs * 32;

  short8 qf[4];
  #pragma unroll
  for (int kk = 0; kk < 4; kk++)
    qf[kk] = *(const short8*)&qp[(size_t)(qrow + col) * 64 + kk * 16 + hi * 8];

  const bool isK = tid < 256;  // wave-uniform (waves 0-3)
  int srcoff, dstoff;
  if (isK) {
    int cc = tid, row = cc >> 3;
    srcoff = row * 64 + (((cc & 7) ^ (row & 7)) * 8);
    dstoff = cc * 8;
  } else {
    int cv = tid - 256, row = cv >> 2;
    srcoff = row * 2048 + (((cv & 3) ^ ((cv >> 3) & 3)) * 8);
    dstoff = 2048 + cv * 8;
  }
  u16* R0 = sStage;            // kh0 region (12288 u16)
  u16* R1 = sStage + 12288;    // kh1 region
  const u16* kbase0 = kg + base;
  const u16* kbase1 = kg + base + 65536;
  const u16* vbase0 = vtg + base;
  const u16* vbase1 = vtg + base + 1024;

  f32x16 o0, o1, zv;
  float lp = 0.f;
  #pragma unroll
  for (int r = 0; r < 16; r++) { o0[r] = 0.f; o1[r] = 0.f; zv[r] = 0.f; }

  const int krsw = (col & 7) << 3;        // K read swizzle (u16 units)
  const int vrsw = ((col >> 1) & 3) << 3; // V read swizzle
  const u16* Rw = sStage + kh * 12288;    // this wave's compute region

  auto STAGE = [&](int tt, int buf) {
    if (isK) {
      gload16(kbase0 + (size_t)tt * 2048 + srcoff, R0 + buf * 4096 + dstoff);
      gload16(kbase1 + (size_t)tt * 2048 + srcoff, R1 + buf * 4096 + dstoff);
    } else {
      gload16(vbase0 + tt * 32 + srcoff, R0 + buf * 4096 + dstoff);
      gload16(vbase1 + tt * 32 + srcoff, R1 + buf * 4096 + dstoff);
    }
  };

  STAGE(0, 0);
  int sel = 0;
  for (int t = 0; t < 32; t++) {
    const int nb = (sel == 2) ? 0 : sel + 1;
    if (t + 1 < 32) {
      STAGE(t + 1, nb);
      asm volatile("s_waitcnt vmcnt(2)" ::: "memory");
    } else {
      asm volatile("s_waitcnt vmcnt(0)" ::: "memory");
    }
    __builtin_amdgcn_s_barrier();
    __builtin_amdgcn_sched_barrier(0);
    const u16* S = Rw + sel * 4096;

    f32x16 st;
    __builtin_amdgcn_s_setprio(1);
    {
      short8 kb = *(const short8*)&S[col * 64 + ((hi * 8) ^ krsw)];
      st = MFMA32(kb, qf[0], zv);
    }
    #pragma unroll
    for (int kk = 1; kk < 4; kk++) {
      short8 kb = *(const short8*)&S[col * 64 + ((kk * 16 + hi * 8) ^ krsw)];
      st = MFMA32(kb, qf[kk], st);
    }
    __builtin_amdgcn_s_setprio(0);

    short8 pa[2];
    softpack1(st, lp, pa[0], pa[1]);

    __builtin_amdgcn_s_setprio(1);
    #pragma unroll
    for (int c = 0; c < 2; c++) {
      short8 vb0 = *(const short8*)&S[2048 + col * 32 + ((c * 16 + hi * 8) ^ vrsw)];
      short8 vb1 = *(const short8*)&S[2048 + (32 + col) * 32 + ((c * 16 + hi * 8) ^ vrsw)];
      o0 = MFMA32(pa[c], vb0, o0);
      o1 = MFMA32(pa[c], vb1, o1);
    }
    __builtin_amdgcn_s_setprio(0);
    sel = nb;
  }

  // merge kv-halves (exact adds thanks to fixed m), then normalize + store
  __syncthreads();
  float* sM = (float*)sStage;            // [qs][32 reg][64 lane] = 8192 floats
  float* sMl = sM + 8192;
  if (kh == 1) {
    #pragma unroll
    for (int r = 0; r < 16; r++) {
      sM[qs * 2048 + r * 64 + l] = o0[r];
      sM[qs * 2048 + (16 + r) * 64 + l] = o1[r];
    }
    sMl[qs * 64 + l] = lp;
  }
  __syncthreads();
  if (kh == 0) {
    #pragma unroll
    for (int r = 0; r < 16; r++) {
      o0[r] += sM[qs * 2048 + r * 64 + l];
      o1[r] += sM[qs * 2048 + (16 + r) * 64 + l];
    }
    lp += sMl[qs * 64 + l];
    float lsum = lp + __shfl_xor(lp, 32);
    if (l < 32) sL2[qs * 32 + col] = 1.0f / lsum;
    __builtin_amdgcn_s_waitcnt(0);  // lgkm drain for same-wave LDS visibility
    const int b = bh >> 4, hh = bh & 15;
    #pragma unroll
    for (int fvt = 0; fvt < 2; fvt++) {
      #pragma unroll
      for (int r = 0; r < 16; r++) {
        int q = (r & 3) + 8 * (r >> 2) + 4 * hi;
        float li = sL2[qs * 32 + q];
        float v = (fvt == 0 ? o0[r] : o1[r]) * li;
        y[((size_t)(b * 2048 + qrow + q)) * 1024 + hh * 64 + fvt * 32 + col] = f2bf(v);
      }
    }
  }
}

// ---------------- launcher ----------------
extern "C" void kernel_launch(void* const* d_in, const int* in_sizes, int n_in,
                              void* d_out, int out_size, void* d_ws, size_t ws_size,
                              hipStream_t stream) {
  const float* x = (const float*)d_in[0];
  const float* w_qkv = (const float*)d_in[1];
  const float* b_qkv = (const float*)d_in[2];
  const float* w_proj = (const float*)d_in[3];
  const float* b_proj = (const float*)d_in[4];
  float* out = (float*)d_out;

  u16* ws = (u16*)d_ws;
  u16* xb = ws;                       // 4,194,304
  u16* wq = xb + 4194304;             // 3,145,728
  u16* wp = wq + 3145728;             // 1,048,576
  u16* qb = wp + 1048576;             // q / k / vt: 3 * 4,194,304
  u16* kb = qb + 4194304;
  u16* vb = kb + 4194304;
  u16* yb = vb + 4194304;             // 4,194,304

  cvt_all<<<8192, 256, 0, stream>>>(x, w_qkv, w_proj, xb, wq, wp);

  gemm_bt<0><<<dim3(24, 32), 256, 0, stream>>>(xb, wq, b_qkv, qb, nullptr, 4096, 3072, 1024);

  attn_kernel<<<512, 512, 0, stream>>>(qb, kb, vb, yb);

  gemm_bt<1><<<dim3(8, 32), 256, 0, stream>>>(yb, wp, b_proj, nullptr, out, 4096, 1024, 1024);
}

// Round 17
// 114.498 us; speedup vs baseline: 1.0055x; 1.0055x over previous
//
#include <hip/hip_runtime.h>
#include <hip/hip_bf16.h>
#include <stdint.h>

// MultiHeadAttention: B=2, L=2048, D=1024, H=16, F=64
// cvt -> GEMM qkv (dbuf stage-ahead, swizzled LDS) -> flash attention (8 waves =
// 4 q-subtiles x 2 kv-halves, KVB=32, RING-4 LDS, 2 tiles per barrier interval)
// -> GEMM proj (fp32 out)
// NOTE 1: launch_bounds min-waves must respect the 64/128/256 VGPR occupancy steps:
//   (256,5) forced VGPR<=64 -> acc spill -> 518MB scratch writes (round 5).
// NOTE 2 (rounds 9-11): ones-MFMA row-sum denominator fails accuracy (~1.3e-2). Keep fp32 lp.
// NOTE 3 (round 13): zv zero-C + cvt_pk_bf16_f32 (RNE) + tree lp-sum verified safe.
// NOTE 4 (round 14): direct global->reg K/V fragment loads are uncoalesced gathers -> LDS only.
// NOTE 5 (round 15/16): stage-at-top + drain-at-bottom already gives loads a full
//   compute phase; ring-3 counted-vmcnt on GEMM was neutral (46.4us) -> reverted to dbuf.
// NOTE 7 (round 17): attn processes 2 tiles per barrier interval (ring-4, 64KB,
//   2 blocks/CU): halves barrier count, dovetails softpack VALU under the other
//   tile's MFMAs. Stages issued AFTER the barrier into bufs (t+2)%4,(t+3)%4.

typedef unsigned short u16;
typedef __attribute__((ext_vector_type(8))) short short8;
typedef __attribute__((ext_vector_type(4))) float f32x4;
typedef __attribute__((ext_vector_type(16))) float f32x16;
typedef __attribute__((ext_vector_type(4))) unsigned int u32x4;

#define MFMA16(a, b, c) __builtin_amdgcn_mfma_f32_16x16x32_bf16((a), (b), (c), 0, 0, 0)
#define MFMA32(a, b, c) __builtin_amdgcn_mfma_f32_32x32x16_bf16((a), (b), (c), 0, 0, 0)

__device__ __forceinline__ u16 f2bf(float x) {
  union { float f; uint32_t u; } v; v.f = x;
  uint32_t r = v.u + 0x7FFFu + ((v.u >> 16) & 1u);
  return (u16)(r >> 16);
}

__device__ __forceinline__ float fexp2(float x) {
#if __has_builtin(__builtin_amdgcn_exp2f)
  return __builtin_amdgcn_exp2f(x);
#else
  return exp2f(x);
#endif
}

// pack two f32 -> two bf16 (round half-up) in one u32 (GEMM epilogue)
__device__ __forceinline__ uint32_t pkbf(float lo, float hi) {
  uint32_t a = __builtin_bit_cast(uint32_t, lo) + 0x8000u;
  uint32_t b = __builtin_bit_cast(uint32_t, hi) + 0x8000u;
  return __builtin_amdgcn_perm(b, a, 0x07060302u);
}

// single-instruction RNE pack: u16[0]=bf16(lo), u16[1]=bf16(hi)
__device__ __forceinline__ uint32_t cvtpk(float lo, float hi) {
  uint32_t r;
  asm("v_cvt_pk_bf16_f32 %0, %1, %2" : "=v"(r) : "v"(lo), "v"(hi));
  return r;
}

__device__ __forceinline__ void gload16(const void* g, void* l) {
  __builtin_amdgcn_global_load_lds((const __attribute__((address_space(1))) void*)g,
                                   (__attribute__((address_space(3))) void*)l, 16, 0, 0);
}

// ---------------- fp32 -> bf16 convert (merged) ----------------
__global__ __launch_bounds__(256) void cvt_all(const float* __restrict__ x,
                                               const float* __restrict__ wq,
                                               const float* __restrict__ wp,
                                               u16* __restrict__ xb,
                                               u16* __restrict__ wqb,
                                               u16* __restrict__ wpb) {
  int i = blockIdx.x * 256 + threadIdx.x;
  const float* s; u16* d; int off;
  if (i < 1048576) { s = x; d = xb; off = i; }
  else if (i < 1835008) { s = wq; d = wqb; off = i - 1048576; }
  else { s = wp; d = wpb; off = i - 1835008; }
  float4 f = reinterpret_cast<const float4*>(s)[off];
  ushort4 o;
  o.x = f2bf(f.x); o.y = f2bf(f.y); o.z = f2bf(f.z); o.w = f2bf(f.w);
  reinterpret_cast<ushort4*>(d)[off] = o;
}

// ---------------- bf16 GEMM: C = A B^T + bias ----------------
// 128x128 tile, BK=32, double-buffered LDS (stage-ahead), slot-swizzled.  [R15-verified]
template <int EPI>
__global__ __launch_bounds__(256, 4) void gemm_bt(const u16* __restrict__ A,
                                                  const u16* __restrict__ B,
                                                  const float* __restrict__ bias,
                                                  u16* __restrict__ outb,
                                                  float* __restrict__ outf,
                                                  int M, int N, int K) {
  __shared__ u16 smem[16384];  // 32 KB
  const int tid = threadIdx.x;
  const int lane = tid & 63;
  const int wid = tid >> 6;
  const int bn = blockIdx.x, bm = blockIdx.y;
  const int row0 = bm * 128, col0 = bn * 128;
  const int wr = wid >> 1, wc = wid & 1;
  const int fr = lane & 15, fq = lane >> 4;

  f32x4 acc[4][4];
  #pragma unroll
  for (int m = 0; m < 4; m++)
    #pragma unroll
    for (int n = 0; n < 4; n++)
      #pragma unroll
      for (int j = 0; j < 4; j++) acc[m][n][j] = 0.f;

  const int cB = tid + 256;
  const int rA1 = tid >> 2, rA2 = cB >> 2;
  const int lA1 = (tid & 3) ^ ((tid >> 3) & 3);
  const int lA2 = (cB & 3) ^ ((cB >> 3) & 3);
  const size_t ga1 = (size_t)rA1 * K + lA1 * 8;
  const size_t ga2 = (size_t)rA2 * K + lA2 * 8;
  const int d1 = tid * 8, d2 = cB * 8;
  const u16* Ab = A + (size_t)row0 * K;
  const u16* Bb = B + (size_t)col0 * K;

  const int sl = (fq ^ ((fr >> 1) & 3)) * 8;
  const int niter = K >> 5;

  {
    u16* s = smem;
    gload16(Ab + ga1, s + d1);
    gload16(Ab + ga2, s + d2);
    gload16(Bb + ga1, s + 4096 + d1);
    gload16(Bb + ga2, s + 4096 + d2);
  }
  __syncthreads();

  for (int t = 0; t < niter; t++) {
    if (t + 1 < niter) {
      u16* s = smem + ((t + 1) & 1) * 8192;
      const size_t k0 = (size_t)(t + 1) * 32;
      gload16(Ab + ga1 + k0, s + d1);
      gload16(Ab + ga2 + k0, s + d2);
      gload16(Bb + ga1 + k0, s + 4096 + d1);
      gload16(Bb + ga2 + k0, s + 4096 + d2);
    }
    const u16* sa = smem + (t & 1) * 8192;
    const u16* sb = sa + 4096;
    short8 a[4], b[4];
    #pragma unroll
    for (int m = 0; m < 4; m++)
      a[m] = *(const short8*)&sa[(wr * 64 + m * 16 + fr) * 32 + sl];
    #pragma unroll
    for (int n = 0; n < 4; n++)
      b[n] = *(const short8*)&sb[(wc * 64 + n * 16 + fr) * 32 + sl];
    __builtin_amdgcn_s_setprio(1);
    #pragma unroll
    for (int m = 0; m < 4; m++)
      #pragma unroll
      for (int n = 0; n < 4; n++)
        acc[m][n] = MFMA16(a[m], b[n], acc[m][n]);
    __builtin_amdgcn_s_setprio(0);
    __syncthreads();
  }

  if (EPI == 0) {
    if (bn < 16) {
      #pragma unroll
      for (int m = 0; m < 4; m++) {
        #pragma unroll
        for (int n = 0; n < 4; n++) {
          #pragma unroll
          for (int j = 0; j < 4; j++) {
            int r = row0 + wr * 64 + m * 16 + fq * 4 + j;
            int c = col0 + wc * 64 + n * 16 + fr;
            float v = acc[m][n][j] + bias[c];
            int d = c & 1023, h = d >> 6, f = d & 63;
            int bb = r >> 11, ll = r & 2047;
            int bhh = bb * 16 + h;
            if (bn < 8) {
              outb[((size_t)bhh * 2048 + ll) * 64 + f] = f2bf(v * 0.18033688f);
            } else {
              outb[4194304u + ((size_t)bhh * 2048 + ll) * 64 + f] = f2bf(v);
            }
          }
        }
      }
    } else {
      u16* sC = smem;
      #pragma unroll
      for (int m = 0; m < 4; m++) {
        #pragma unroll
        for (int n = 0; n < 4; n++) {
          int c_local = wc * 64 + n * 16 + fr;
          int r_base = wr * 64 + m * 16 + fq * 4;
          float bi = bias[col0 + c_local];
          uint2 w;
          w.x = pkbf(acc[m][n][0] + bi, acc[m][n][1] + bi);
          w.y = pkbf(acc[m][n][2] + bi, acc[m][n][3] + bi);
          *(uint2*)&sC[c_local * 128 + (r_base ^ ((c_local & 7) << 3))] = w;
        }
      }
      __syncthreads();
      const int h0 = (col0 - 2048) >> 6;
      const int ll0 = row0 & 2047;
      const int bb = row0 >> 11;
      #pragma unroll
      for (int it = 0; it < 8; it++) {
        int chunk = tid + it * 256;
        int row_c = chunk >> 4, off = chunk & 15;
        short8 v = *(const short8*)&sC[row_c * 128 + ((off * 8) ^ ((row_c & 7) << 3))];
        int h = h0 + (row_c >> 6), f = row_c & 63;
        *(short8*)&outb[8388608u + ((size_t)((bb * 16 + h) * 64 + f)) * 2048 + ll0 + off * 8] = v;
      }
    }
  } else {
    #pragma unroll
    for (int m = 0; m < 4; m++)
      #pragma unroll
      for (int n = 0; n < 4; n++)
        #pragma unroll
        for (int j = 0; j < 4; j++) {
          int r = row0 + wr * 64 + m * 16 + fq * 4 + j;
          int c = col0 + wc * 64 + n * 16 + fr;
          outf[(size_t)r * N + c] = acc[m][n][j] + bias[c];
        }
  }
}

// ---------------- flash attention (ring-4, 2 tiles per barrier interval) ----------------
// 512 thr / 8 waves: wave(qs=wid&3, kh=wid>>2) = 32 q rows x kv-half (1024), KVB=32.
__device__ __forceinline__ void softpack1(const f32x16& st, float& lp,
                                          short8& paA, short8& paB) {
  float e[16];
  #pragma unroll
  for (int r = 0; r < 16; r++) e[r] = fexp2(st[r]);
  float s0 = (e[0] + e[1]) + (e[2] + e[3]);
  float s1 = (e[4] + e[5]) + (e[6] + e[7]);
  float s2 = (e[8] + e[9]) + (e[10] + e[11]);
  float s3 = (e[12] + e[13]) + (e[14] + e[15]);
  lp += (s0 + s1) + (s2 + s3);
  #pragma unroll
  for (int cc = 0; cc < 2; cc++) {
    uint32_t g0 = cvtpk(e[8 * cc + 0], e[8 * cc + 1]);
    uint32_t g1 = cvtpk(e[8 * cc + 2], e[8 * cc + 3]);
    uint32_t g2 = cvtpk(e[8 * cc + 4], e[8 * cc + 5]);
    uint32_t g3 = cvtpk(e[8 * cc + 6], e[8 * cc + 7]);
    asm volatile("v_permlane32_swap_b32 %0, %1" : "+v"(g0), "+v"(g2));
    asm volatile("v_permlane32_swap_b32 %0, %1" : "+v"(g1), "+v"(g3));
    u32x4 t;
    t[0] = g0; t[1] = g1; t[2] = g2; t[3] = g3;
    if (cc == 0) paA = __builtin_bit_cast(short8, t);
    else paB = __builtin_bit_cast(short8, t);
  }
}

__global__ __launch_bounds__(512, 4) void attn_kernel(const u16* __restrict__ qg,
                                                      const u16* __restrict__ kg,
                                                      const u16* __restrict__ vtg,
                                                      u16* __restrict__ y) {
  __shared__ u16 sStage[32768];  // 64 KB: [kh][4 bufs][K 2048 | V 2048] u16
  __shared__ float sL2[128];
  const int x = blockIdx.x;
  const int bh = (x & 7) * 4 + (x >> 7);   // 4 bh per XCD -> K/V L2-resident
  const int qt = (x >> 3) & 15;
  const int tid = threadIdx.x, l = tid & 63, wid = tid >> 6;
  const int qs = wid & 3, kh = wid >> 2;
  const int col = l & 31, hi = l >> 5;
  const size_t base = (size_t)bh * 131072;
  const u16* qp = qg + base;
  const int qrow = qt * 128 + qs * 32;

  short8 qf[4];
  #pragma unroll
  for (int kk = 0; kk < 4; kk++)
    qf[kk] = *(const short8*)&qp[(size_t)(qrow + col) * 64 + kk * 16 + hi * 8];

  const bool isK = tid < 256;  // wave-uniform (waves 0-3 stage K, 4-7 stage V)
  int srcoff, dstoff;
  if (isK) {
    int cc = tid, row = cc >> 3;
    srcoff = row * 64 + (((cc & 7) ^ (row & 7)) * 8);
    dstoff = cc * 8;
  } else {
    int cv = tid - 256, row = cv >> 2;
    srcoff = row * 2048 + (((cv & 3) ^ ((cv >> 3) & 3)) * 8);
    dstoff = 2048 + cv * 8;
  }
  u16* R0 = sStage;            // kh0 region (16384 u16)
  u16* R1 = sStage + 16384;    // kh1 region
  const u16* kbase0 = kg + base;
  const u16* kbase1 = kg + base + 65536;
  const u16* vbase0 = vtg + base;
  const u16* vbase1 = vtg + base + 1024;

  f32x16 o0, o1, zv;
  float lp = 0.f;
  #pragma unroll
  for (int r = 0; r < 16; r++) { o0[r] = 0.f; o1[r] = 0.f; zv[r] = 0.f; }

  const int krsw = (col & 7) << 3;        // K read swizzle (u16 units)
  const int vrsw = ((col >> 1) & 3) << 3; // V read swizzle
  const u16* Rw = sStage + kh * 16384;    // this wave's compute region

  auto STAGE = [&](int tt) {
    const int buf = tt & 3;
    if (isK) {
      gload16(kbase0 + (size_t)tt * 2048 + srcoff, R0 + buf * 4096 + dstoff);
      gload16(kbase1 + (size_t)tt * 2048 + srcoff, R1 + buf * 4096 + dstoff);
    } else {
      gload16(vbase0 + tt * 32 + srcoff, R0 + buf * 4096 + dstoff);
      gload16(vbase1 + tt * 32 + srcoff, R1 + buf * 4096 + dstoff);
    }
  };

  auto QK = [&](const u16* S) -> f32x16 {
    f32x16 st;
    __builtin_amdgcn_s_setprio(1);
    {
      short8 kb = *(const short8*)&S[col * 64 + ((hi * 8) ^ krsw)];
      st = MFMA32(kb, qf[0], zv);
    }
    #pragma unroll
    for (int kk = 1; kk < 4; kk++) {
      short8 kb = *(const short8*)&S[col * 64 + ((kk * 16 + hi * 8) ^ krsw)];
      st = MFMA32(kb, qf[kk], st);
    }
    __builtin_amdgcn_s_setprio(0);
    return st;
  };

  auto PV = [&](const u16* S, short8* pa) {
    __builtin_amdgcn_s_setprio(1);
    #pragma unroll
    for (int c = 0; c < 2; c++) {
      short8 vb0 = *(const short8*)&S[2048 + col * 32 + ((c * 16 + hi * 8) ^ vrsw)];
      short8 vb1 = *(const short8*)&S[2048 + (32 + col) * 32 + ((c * 16 + hi * 8) ^ vrsw)];
      o0 = MFMA32(pa[c], vb0, o0);
      o1 = MFMA32(pa[c], vb1, o1);
    }
    __builtin_amdgcn_s_setprio(0);
  };

  // prologue: tiles 0,1 -> bufs 0,1
  STAGE(0);
  STAGE(1);
  for (int t = 0; t < 32; t += 2) {
    asm volatile("s_waitcnt vmcnt(0)" ::: "memory");  // loads from prev interval (full interval old)
    __builtin_amdgcn_s_barrier();
    __builtin_amdgcn_sched_barrier(0);
    if (t + 2 < 32) STAGE(t + 2);
    if (t + 3 < 32) STAGE(t + 3);
    const u16* SA = Rw + (t & 3) * 4096;
    const u16* SB = Rw + ((t + 1) & 3) * 4096;
    f32x16 stA = QK(SA);
    f32x16 stB = QK(SB);
    short8 pa[2], pb[2];
    softpack1(stA, lp, pa[0], pa[1]);  // VALU overlaps stB's MFMAs
    PV(SA, pa);
    softpack1(stB, lp, pb[0], pb[1]);  // VALU overlaps PV(A)'s MFMAs
    PV(SB, pb);
  }

  // merge kv-halves (exact adds thanks to fixed m), then normalize + store
  __syncthreads();
  float* sM = (float*)sStage;            // [qs][32 reg][64 lane] = 8192 floats
  float* sMl = sM + 8192;
  if (kh == 1) {
    #pragma unroll
    for (int r = 0; r < 16; r++) {
      sM[qs * 2048 + r * 64 + l] = o0[r];
      sM[qs * 2048 + (16 + r) * 64 + l] = o1[r];
    }
    sMl[qs * 64 + l] = lp;
  }
  __syncthreads();
  if (kh == 0) {
    #pragma unroll
    for (int r = 0; r < 16; r++) {
      o0[r] += sM[qs * 2048 + r * 64 + l];
      o1[r] += sM[qs * 2048 + (16 + r) * 64 + l];
    }
    lp += sMl[qs * 64 + l];
    float lsum = lp + __shfl_xor(lp, 32);
    if (l < 32) sL2[qs * 32 + col] = 1.0f / lsum;
    __builtin_amdgcn_s_waitcnt(0);  // lgkm drain for same-wave LDS visibility
    const int b = bh >> 4, hh = bh & 15;
    #pragma unroll
    for (int fvt = 0; fvt < 2; fvt++) {
      #pragma unroll
      for (int r = 0; r < 16; r++) {
        int q = (r & 3) + 8 * (r >> 2) + 4 * hi;
        float li = sL2[qs * 32 + q];
        float v = (fvt == 0 ? o0[r] : o1[r]) * li;
        y[((size_t)(b * 2048 + qrow + q)) * 1024 + hh * 64 + fvt * 32 + col] = f2bf(v);
      }
    }
  }
}

// ---------------- launcher ----------------
extern "C" void kernel_launch(void* const* d_in, const int* in_sizes, int n_in,
                              void* d_out, int out_size, void* d_ws, size_t ws_size,
                              hipStream_t stream) {
  const float* x = (const float*)d_in[0];
  const float* w_qkv = (const float*)d_in[1];
  const float* b_qkv = (const float*)d_in[2];
  const float* w_proj = (const float*)d_in[3];
  const float* b_proj = (const float*)d_in[4];
  float* out = (float*)d_out;

  u16* ws = (u16*)d_ws;
  u16* xb = ws;                       // 4,194,304
  u16* wq = xb + 4194304;             // 3,145,728
  u16* wp = wq + 3145728;             // 1,048,576
  u16* qb = wp + 1048576;             // q / k / vt: 3 * 4,194,304
  u16* kb = qb + 4194304;
  u16* vb = kb + 4194304;
  u16* yb = vb + 4194304;             // 4,194,304

  cvt_all<<<8192, 256, 0, stream>>>(x, w_qkv, w_proj, xb, wq, wp);

  gemm_bt<0><<<dim3(24, 32), 256, 0, stream>>>(xb, wq, b_qkv, qb, nullptr, 4096, 3072, 1024);

  attn_kernel<<<512, 512, 0, stream>>>(qb, kb, vb, yb);

  gemm_bt<1><<<dim3(8, 32), 256, 0, stream>>>(yb, wp, b_proj, nullptr, out, 4096, 1024, 1024);
}

// Round 19
// 112.436 us; speedup vs baseline: 1.0240x; 1.0183x over previous
//
#include <hip/hip_runtime.h>
#include <hip/hip_bf16.h>
#include <stdint.h>

// MultiHeadAttention: B=2, L=2048, D=1024, H=16, F=64
// cvt -> GEMM qkv (dbuf stage-ahead, swizzled LDS) -> flash attention (8 waves =
// 4 q-subtiles x 2 kv-halves, KVB=64 per barrier interval, 2 sequential 32-kv
// sub-tiles, 2-buf LDS, R6-style sync: stage at top, vmcnt(0)+barrier AFTER compute)
// -> GEMM proj (fp32 out)
// NOTE 1: launch_bounds min-waves must respect the 64/128/256 VGPR occupancy steps.
// NOTE 2 (r9-11): ones-MFMA row-sum denominator fails accuracy. Keep fp32 lp.
// NOTE 3 (r13): zv zero-C + cvt_pk_bf16_f32 (RNE) + tree lp-sum verified safe.
// NOTE 4 (r14): K/V fragment loads must go through LDS staging (gathers otherwise).
// NOTE 7 (r17): keeping two st tiles live spills (VGPR cap 64) -> one st at a time.
// NOTE 8 (r18): 2-buf + barrier-BEFORE-compute races (laggard waves read the buf the
//   next stage overwrites: (t+1)%2 == (t-1)%2) -> 4.2e-2. Safe orderings: ring-3 with
//   pre-barrier stage (R15), or 2-buf with stage-at-top + barrier-AFTER-compute (R6,
//   this round). Never 2-buf + pre-barrier stage.

typedef unsigned short u16;
typedef __attribute__((ext_vector_type(8))) short short8;
typedef __attribute__((ext_vector_type(4))) float f32x4;
typedef __attribute__((ext_vector_type(16))) float f32x16;
typedef __attribute__((ext_vector_type(4))) unsigned int u32x4;

#define MFMA16(a, b, c) __builtin_amdgcn_mfma_f32_16x16x32_bf16((a), (b), (c), 0, 0, 0)
#define MFMA32(a, b, c) __builtin_amdgcn_mfma_f32_32x32x16_bf16((a), (b), (c), 0, 0, 0)

__device__ __forceinline__ u16 f2bf(float x) {
  union { float f; uint32_t u; } v; v.f = x;
  uint32_t r = v.u + 0x7FFFu + ((v.u >> 16) & 1u);
  return (u16)(r >> 16);
}

__device__ __forceinline__ float fexp2(float x) {
#if __has_builtin(__builtin_amdgcn_exp2f)
  return __builtin_amdgcn_exp2f(x);
#else
  return exp2f(x);
#endif
}

// pack two f32 -> two bf16 (round half-up) in one u32 (GEMM epilogue)
__device__ __forceinline__ uint32_t pkbf(float lo, float hi) {
  uint32_t a = __builtin_bit_cast(uint32_t, lo) + 0x8000u;
  uint32_t b = __builtin_bit_cast(uint32_t, hi) + 0x8000u;
  return __builtin_amdgcn_perm(b, a, 0x07060302u);
}

// single-instruction RNE pack: u16[0]=bf16(lo), u16[1]=bf16(hi)
__device__ __forceinline__ uint32_t cvtpk(float lo, float hi) {
  uint32_t r;
  asm("v_cvt_pk_bf16_f32 %0, %1, %2" : "=v"(r) : "v"(lo), "v"(hi));
  return r;
}

__device__ __forceinline__ void gload16(const void* g, void* l) {
  __builtin_amdgcn_global_load_lds((const __attribute__((address_space(1))) void*)g,
                                   (__attribute__((address_space(3))) void*)l, 16, 0, 0);
}

// ---------------- fp32 -> bf16 convert (merged) ----------------
__global__ __launch_bounds__(256) void cvt_all(const float* __restrict__ x,
                                               const float* __restrict__ wq,
                                               const float* __restrict__ wp,
                                               u16* __restrict__ xb,
                                               u16* __restrict__ wqb,
                                               u16* __restrict__ wpb) {
  int i = blockIdx.x * 256 + threadIdx.x;
  const float* s; u16* d; int off;
  if (i < 1048576) { s = x; d = xb; off = i; }
  else if (i < 1835008) { s = wq; d = wqb; off = i - 1048576; }
  else { s = wp; d = wpb; off = i - 1835008; }
  float4 f = reinterpret_cast<const float4*>(s)[off];
  ushort4 o;
  o.x = f2bf(f.x); o.y = f2bf(f.y); o.z = f2bf(f.z); o.w = f2bf(f.w);
  reinterpret_cast<ushort4*>(d)[off] = o;
}

// ---------------- bf16 GEMM: C = A B^T + bias ----------------
// 128x128 tile, BK=32, double-buffered LDS (stage-ahead), slot-swizzled.  [R6/R15-verified]
template <int EPI>
__global__ __launch_bounds__(256, 4) void gemm_bt(const u16* __restrict__ A,
                                                  const u16* __restrict__ B,
                                                  const float* __restrict__ bias,
                                                  u16* __restrict__ outb,
                                                  float* __restrict__ outf,
                                                  int M, int N, int K) {
  __shared__ u16 smem[16384];  // 32 KB
  const int tid = threadIdx.x;
  const int lane = tid & 63;
  const int wid = tid >> 6;
  const int bn = blockIdx.x, bm = blockIdx.y;
  const int row0 = bm * 128, col0 = bn * 128;
  const int wr = wid >> 1, wc = wid & 1;
  const int fr = lane & 15, fq = lane >> 4;

  f32x4 acc[4][4];
  #pragma unroll
  for (int m = 0; m < 4; m++)
    #pragma unroll
    for (int n = 0; n < 4; n++)
      #pragma unroll
      for (int j = 0; j < 4; j++) acc[m][n][j] = 0.f;

  const int cB = tid + 256;
  const int rA1 = tid >> 2, rA2 = cB >> 2;
  const int lA1 = (tid & 3) ^ ((tid >> 3) & 3);
  const int lA2 = (cB & 3) ^ ((cB >> 3) & 3);
  const size_t ga1 = (size_t)rA1 * K + lA1 * 8;
  const size_t ga2 = (size_t)rA2 * K + lA2 * 8;
  const int d1 = tid * 8, d2 = cB * 8;
  const u16* Ab = A + (size_t)row0 * K;
  const u16* Bb = B + (size_t)col0 * K;

  const int sl = (fq ^ ((fr >> 1) & 3)) * 8;
  const int niter = K >> 5;

  {
    u16* s = smem;
    gload16(Ab + ga1, s + d1);
    gload16(Ab + ga2, s + d2);
    gload16(Bb + ga1, s + 4096 + d1);
    gload16(Bb + ga2, s + 4096 + d2);
  }
  __syncthreads();

  for (int t = 0; t < niter; t++) {
    if (t + 1 < niter) {
      u16* s = smem + ((t + 1) & 1) * 8192;
      const size_t k0 = (size_t)(t + 1) * 32;
      gload16(Ab + ga1 + k0, s + d1);
      gload16(Ab + ga2 + k0, s + d2);
      gload16(Bb + ga1 + k0, s + 4096 + d1);
      gload16(Bb + ga2 + k0, s + 4096 + d2);
    }
    const u16* sa = smem + (t & 1) * 8192;
    const u16* sb = sa + 4096;
    short8 a[4], b[4];
    #pragma unroll
    for (int m = 0; m < 4; m++)
      a[m] = *(const short8*)&sa[(wr * 64 + m * 16 + fr) * 32 + sl];
    #pragma unroll
    for (int n = 0; n < 4; n++)
      b[n] = *(const short8*)&sb[(wc * 64 + n * 16 + fr) * 32 + sl];
    __builtin_amdgcn_s_setprio(1);
    #pragma unroll
    for (int m = 0; m < 4; m++)
      #pragma unroll
      for (int n = 0; n < 4; n++)
        acc[m][n] = MFMA16(a[m], b[n], acc[m][n]);
    __builtin_amdgcn_s_setprio(0);
    __syncthreads();
  }

  if (EPI == 0) {
    if (bn < 16) {
      #pragma unroll
      for (int m = 0; m < 4; m++) {
        #pragma unroll
        for (int n = 0; n < 4; n++) {
          #pragma unroll
          for (int j = 0; j < 4; j++) {
            int r = row0 + wr * 64 + m * 16 + fq * 4 + j;
            int c = col0 + wc * 64 + n * 16 + fr;
            float v = acc[m][n][j] + bias[c];
            int d = c & 1023, h = d >> 6, f = d & 63;
            int bb = r >> 11, ll = r & 2047;
            int bhh = bb * 16 + h;
            if (bn < 8) {
              outb[((size_t)bhh * 2048 + ll) * 64 + f] = f2bf(v * 0.18033688f);
            } else {
              outb[4194304u + ((size_t)bhh * 2048 + ll) * 64 + f] = f2bf(v);
            }
          }
        }
      }
    } else {
      u16* sC = smem;
      #pragma unroll
      for (int m = 0; m < 4; m++) {
        #pragma unroll
        for (int n = 0; n < 4; n++) {
          int c_local = wc * 64 + n * 16 + fr;
          int r_base = wr * 64 + m * 16 + fq * 4;
          float bi = bias[col0 + c_local];
          uint2 w;
          w.x = pkbf(acc[m][n][0] + bi, acc[m][n][1] + bi);
          w.y = pkbf(acc[m][n][2] + bi, acc[m][n][3] + bi);
          *(uint2*)&sC[c_local * 128 + (r_base ^ ((c_local & 7) << 3))] = w;
        }
      }
      __syncthreads();
      const int h0 = (col0 - 2048) >> 6;
      const int ll0 = row0 & 2047;
      const int bb = row0 >> 11;
      #pragma unroll
      for (int it = 0; it < 8; it++) {
        int chunk = tid + it * 256;
        int row_c = chunk >> 4, off = chunk & 15;
        short8 v = *(const short8*)&sC[row_c * 128 + ((off * 8) ^ ((row_c & 7) << 3))];
        int h = h0 + (row_c >> 6), f = row_c & 63;
        *(short8*)&outb[8388608u + ((size_t)((bb * 16 + h) * 64 + f)) * 2048 + ll0 + off * 8] = v;
      }
    }
  } else {
    #pragma unroll
    for (int m = 0; m < 4; m++)
      #pragma unroll
      for (int n = 0; n < 4; n++)
        #pragma unroll
        for (int j = 0; j < 4; j++) {
          int r = row0 + wr * 64 + m * 16 + fq * 4 + j;
          int c = col0 + wc * 64 + n * 16 + fr;
          outf[(size_t)r * N + c] = acc[m][n][j] + bias[c];
        }
  }
}

// ---------------- flash attention (KVB=64/interval, race-free 2-buf) ----------------
// 512 thr / 8 waves: wave(qs=wid&3, kh=wid>>2) = 32 q rows x kv-half (1024).
// Per interval: stage next K[64][64]+V^T[64][64] (both kh) at TOP, compute two 32-kv
// sub-tiles from current buf, then vmcnt(0)+barrier at BOTTOM (R6 ordering -> no WAR).
__device__ __forceinline__ void softpack1(const f32x16& st, float& lp,
                                          short8& paA, short8& paB) {
  float e[16];
  #pragma unroll
  for (int r = 0; r < 16; r++) e[r] = fexp2(st[r]);
  float s0 = (e[0] + e[1]) + (e[2] + e[3]);
  float s1 = (e[4] + e[5]) + (e[6] + e[7]);
  float s2 = (e[8] + e[9]) + (e[10] + e[11]);
  float s3 = (e[12] + e[13]) + (e[14] + e[15]);
  lp += (s0 + s1) + (s2 + s3);
  #pragma unroll
  for (int cc = 0; cc < 2; cc++) {
    uint32_t g0 = cvtpk(e[8 * cc + 0], e[8 * cc + 1]);
    uint32_t g1 = cvtpk(e[8 * cc + 2], e[8 * cc + 3]);
    uint32_t g2 = cvtpk(e[8 * cc + 4], e[8 * cc + 5]);
    uint32_t g3 = cvtpk(e[8 * cc + 6], e[8 * cc + 7]);
    asm volatile("v_permlane32_swap_b32 %0, %1" : "+v"(g0), "+v"(g2));
    asm volatile("v_permlane32_swap_b32 %0, %1" : "+v"(g1), "+v"(g3));
    u32x4 t;
    t[0] = g0; t[1] = g1; t[2] = g2; t[3] = g3;
    if (cc == 0) paA = __builtin_bit_cast(short8, t);
    else paB = __builtin_bit_cast(short8, t);
  }
}

__global__ __launch_bounds__(512, 4) void attn_kernel(const u16* __restrict__ qg,
                                                      const u16* __restrict__ kg,
                                                      const u16* __restrict__ vtg,
                                                      u16* __restrict__ y) {
  __shared__ u16 sStage[32768];  // 64 KB: [kh][2 bufs][K 4096 | V 4096] u16
  __shared__ float sL2[128];
  const int x = blockIdx.x;
  const int bh = (x & 7) * 4 + (x >> 7);   // 4 bh per XCD -> K/V L2-resident
  const int qt = (x >> 3) & 15;
  const int tid = threadIdx.x, l = tid & 63, wid = tid >> 6;
  const int qs = wid & 3, kh = wid >> 2;
  const int col = l & 31, hi = l >> 5;
  const size_t base = (size_t)bh * 131072;
  const u16* qp = qg + base;
  const int qrow = qt * 128 + qs * 32;

  short8 qf[4];
  #pragma unroll
  for (int kk = 0; kk < 4; kk++)
    qf[kk] = *(const short8*)&qp[(size_t)(qrow + col) * 64 + kk * 16 + hi * 8];

  // staging: K threads (tid<256) stage K chunks {tid, tid+256}; V threads (tid>=256)
  // stage V chunks {tid-256, tid-256+256}; each for both kh -> 4 gload16/interval.
  // K tile [64 kv][64 f], V tile [64 f][64 kv]: chunk c -> row c>>3, phys slot c&7,
  // src slot (c&7)^(row&7).
  const bool isK = tid < 256;  // wave-uniform
  const int ca = isK ? tid : (tid - 256);
  const int cb = ca + 256;
  int srcA, srcB, dstA, dstB;
  {
    int rA = ca >> 3, rB = cb >> 3;
    int rowstride = isK ? 64 : 2048;
    srcA = rA * rowstride + (((ca & 7) ^ (rA & 7)) * 8);
    srcB = rB * rowstride + (((cb & 7) ^ (rB & 7)) * 8);
    dstA = (isK ? 0 : 4096) + ca * 8;
    dstB = (isK ? 0 : 4096) + cb * 8;
  }
  u16* R0 = sStage;            // kh0 region (16384 u16)
  u16* R1 = sStage + 16384;    // kh1 region
  const u16* gb0 = isK ? (kg + base) : (vtg + base);
  const u16* gb1 = isK ? (kg + base + 65536) : (vtg + base + 1024);

  f32x16 o0, o1, zv;
  float lp = 0.f;
  #pragma unroll
  for (int r = 0; r < 16; r++) { o0[r] = 0.f; o1[r] = 0.f; zv[r] = 0.f; }

  const int rsw = (col & 7) << 3;         // read swizzle (row&7 == col&7 for all reads)
  const u16* Rw = sStage + kh * 16384;    // this wave's compute region

  auto STAGE = [&](int tt, int buf) {
    const size_t toff = isK ? (size_t)tt * 4096 : (size_t)tt * 64;
    gload16(gb0 + toff + srcA, R0 + buf * 8192 + dstA);
    gload16(gb1 + toff + srcA, R1 + buf * 8192 + dstA);
    gload16(gb0 + toff + srcB, R0 + buf * 8192 + dstB);
    gload16(gb1 + toff + srcB, R1 + buf * 8192 + dstB);
  };

  // prologue: interval 0 -> buf 0, drain, sync
  STAGE(0, 0);
  asm volatile("s_waitcnt vmcnt(0)" ::: "memory");
  __builtin_amdgcn_s_barrier();
  __builtin_amdgcn_sched_barrier(0);

  int sel = 0;
  for (int t = 0; t < 16; t++) {
    const int nb = sel ^ 1;
    if (t + 1 < 16) STAGE(t + 1, nb);   // writes nb; all waves past barrier t-1 -> no WAR
    const u16* S = Rw + sel * 8192;

    #pragma unroll
    for (int sub = 0; sub < 2; sub++) {
      const u16* Ks = S + sub * 2048;   // kv rows sub*32.., row stride 64
      f32x16 st;
      __builtin_amdgcn_s_setprio(1);
      {
        short8 kb = *(const short8*)&Ks[col * 64 + ((hi * 8) ^ rsw)];
        st = MFMA32(kb, qf[0], zv);
      }
      #pragma unroll
      for (int kk = 1; kk < 4; kk++) {
        short8 kb = *(const short8*)&Ks[col * 64 + ((kk * 16 + hi * 8) ^ rsw)];
        st = MFMA32(kb, qf[kk], st);
      }
      __builtin_amdgcn_s_setprio(0);

      short8 pa[2];
      softpack1(st, lp, pa[0], pa[1]);

      __builtin_amdgcn_s_setprio(1);
      #pragma unroll
      for (int c = 0; c < 2; c++) {
        short8 vb0 = *(const short8*)&S[4096 + col * 64 + ((sub * 32 + c * 16 + hi * 8) ^ rsw)];
        short8 vb1 = *(const short8*)&S[4096 + (32 + col) * 64 + ((sub * 32 + c * 16 + hi * 8) ^ rsw)];
        o0 = MFMA32(pa[c], vb0, o0);
        o1 = MFMA32(pa[c], vb1, o1);
      }
      __builtin_amdgcn_s_setprio(0);
    }

    asm volatile("s_waitcnt vmcnt(0)" ::: "memory");  // next-interval loads landed (issued pre-compute)
    __builtin_amdgcn_s_barrier();
    __builtin_amdgcn_sched_barrier(0);
    sel = nb;
  }

  // merge kv-halves (exact adds thanks to fixed m), then normalize + store
  float* sM = (float*)sStage;            // [qs][32 reg][64 lane] = 8192 floats
  float* sMl = sM + 8192;
  if (kh == 1) {
    #pragma unroll
    for (int r = 0; r < 16; r++) {
      sM[qs * 2048 + r * 64 + l] = o0[r];
      sM[qs * 2048 + (16 + r) * 64 + l] = o1[r];
    }
    sMl[qs * 64 + l] = lp;
  }
  __syncthreads();
  if (kh == 0) {
    #pragma unroll
    for (int r = 0; r < 16; r++) {
      o0[r] += sM[qs * 2048 + r * 64 + l];
      o1[r] += sM[qs * 2048 + (16 + r) * 64 + l];
    }
    lp += sMl[qs * 64 + l];
    float lsum = lp + __shfl_xor(lp, 32);
    if (l < 32) sL2[qs * 32 + col] = 1.0f / lsum;
    __builtin_amdgcn_s_waitcnt(0);  // lgkm drain for same-wave LDS visibility
    const int b = bh >> 4, hh = bh & 15;
    #pragma unroll
    for (int fvt = 0; fvt < 2; fvt++) {
      #pragma unroll
      for (int r = 0; r < 16; r++) {
        int q = (r & 3) + 8 * (r >> 2) + 4 * hi;
        float li = sL2[qs * 32 + q];
        float v = (fvt == 0 ? o0[r] : o1[r]) * li;
        y[((size_t)(b * 2048 + qrow + q)) * 1024 + hh * 64 + fvt * 32 + col] = f2bf(v);
      }
    }
  }
}

// ---------------- launcher ----------------
extern "C" void kernel_launch(void* const* d_in, const int* in_sizes, int n_in,
                              void* d_out, int out_size, void* d_ws, size_t ws_size,
                              hipStream_t stream) {
  const float* x = (const float*)d_in[0];
  const float* w_qkv = (const float*)d_in[1];
  const float* b_qkv = (const float*)d_in[2];
  const float* w_proj = (const float*)d_in[3];
  const float* b_proj = (const float*)d_in[4];
  float* out = (float*)d_out;

  u16* ws = (u16*)d_ws;
  u16* xb = ws;                       // 4,194,304
  u16* wq = xb + 4194304;             // 3,145,728
  u16* wp = wq + 3145728;             // 1,048,576
  u16* qb = wp + 1048576;             // q / k / vt: 3 * 4,194,304
  u16* kb = qb + 4194304;
  u16* vb = kb + 4194304;
  u16* yb = vb + 4194304;             // 4,194,304

  cvt_all<<<8192, 256, 0, stream>>>(x, w_qkv, w_proj, xb, wq, wp);

  gemm_bt<0><<<dim3(24, 32), 256, 0, stream>>>(xb, wq, b_qkv, qb, nullptr, 4096, 3072, 1024);

  attn_kernel<<<512, 512, 0, stream>>>(qb, kb, vb, yb);

  gemm_bt<1><<<dim3(8, 32), 256, 0, stream>>>(yb, wp, b_proj, nullptr, out, 4096, 1024, 1024);
}